// Round 1
// baseline (1177.360 us; speedup 1.0000x reference)
//
#include <hip/hip_runtime.h>

typedef float f32x4 __attribute__((ext_vector_type(4)));
typedef __bf16 bf16x8 __attribute__((ext_vector_type(8)));
typedef unsigned int u32x4 __attribute__((ext_vector_type(4)));

#define DEVINL __device__ __forceinline__

constexpr int N_NODES = 23040;
constexpr int N_EDGES = 368640;
constexpr int NGRAPH  = 64;
constexpr int TSTEPS  = 360;
constexpr int HID     = 256;

// ---------- helpers ----------
DEVINL unsigned short f2bf(float x) { __bf16 b = (__bf16)x; unsigned short u; __builtin_memcpy(&u, &b, 2); return u; }
DEVINL float bf2f(unsigned short u) { __bf16 b; __builtin_memcpy(&b, &u, 2); return (float)b; }

DEVINL void cvt8(const float* x, unsigned int* hp, unsigned int* lp) {
#pragma unroll
  for (int d = 0; d < 4; ++d) {
    unsigned short h0 = f2bf(x[2*d]), h1 = f2bf(x[2*d+1]);
    float r0 = x[2*d] - bf2f(h0), r1 = x[2*d+1] - bf2f(h1);
    unsigned short l0 = f2bf(r0), l1 = f2bf(r1);
    hp[d] = (unsigned int)h0 | ((unsigned int)h1 << 16);
    lp[d] = (unsigned int)l0 | ((unsigned int)l1 << 16);
  }
}

DEVINL float sig_(float x) { return 1.f / (1.f + __expf(-x)); }
DEVINL float tanh_(float x) { float e = __expf(2.f * x); return 1.f - 2.f / (e + 1.f); }

// ---------- graph structure ----------
__global__ __launch_bounds__(256) void count_kernel(const int* __restrict__ dst, int* __restrict__ cnt) {
  int e = blockIdx.x * 256 + threadIdx.x;
  if (e < N_EDGES) atomicAdd(&cnt[dst[e]], 1);
}

__global__ __launch_bounds__(256) void deg_kernel(const int* __restrict__ cnt, float* __restrict__ isq, float* __restrict__ idg) {
  int n = blockIdx.x * 256 + threadIdx.x;
  if (n < N_NODES) {
    float d = (float)cnt[n] + 1.0f;
    isq[n] = rsqrtf(d);
    idg[n] = 1.0f / d;
  }
}

__global__ __launch_bounds__(1024) void scan_kernel(const int* __restrict__ cnt, int* __restrict__ rp) {
  __shared__ int wsum[16];
  __shared__ int wpre[16];
  int tid = threadIdx.x, lane = tid & 63, wid = tid >> 6;
  int run = 0;
  if (tid == 0) rp[0] = 0;
  for (int base = 0; base < N_NODES; base += 1024) {
    int i = base + tid;
    int v = (i < N_NODES) ? cnt[i] : 0;
    int s = v;
#pragma unroll
    for (int off = 1; off < 64; off <<= 1) { int t = __shfl_up(s, off); if (lane >= off) s += t; }
    if (lane == 63) wsum[wid] = s;
    __syncthreads();
    if (wid == 0) {
      int ws = (lane < 16) ? wsum[lane] : 0;
#pragma unroll
      for (int off = 1; off < 16; off <<= 1) { int t = __shfl_up(ws, off); if (lane >= off) ws += t; }
      if (lane < 16) wpre[lane] = ws;
    }
    __syncthreads();
    int wofs = (wid > 0) ? wpre[wid - 1] : 0;
    if (i < N_NODES) rp[i + 1] = run + wofs + s;
    run += wpre[15];
    __syncthreads();
  }
}

__global__ __launch_bounds__(256) void fill_kernel(const int* __restrict__ src, const int* __restrict__ dst,
                                                   const int* __restrict__ rp, int* __restrict__ cur,
                                                   int* __restrict__ cs) {
  int e = blockIdx.x * 256 + threadIdx.x;
  if (e < N_EDGES) {
    int d = dst[e];
    int pos = rp[d] + atomicAdd(&cur[d], 1);
    cs[pos] = src[e];
  }
}

// ---------- weight preconversion: [K x 256] fp32 -> tiled bf16 hi/lo planes ----------
__global__ __launch_bounds__(256) void prep_w_kernel(const float* __restrict__ W, int K, int ntiles,
                                                     unsigned int* __restrict__ ph, unsigned int* __restrict__ pl) {
  int idx = blockIdx.x * 256 + threadIdx.x;
  int c = idx & 255;
  int rest = idx >> 8;
  int dp = rest & 3; rest >>= 2;
  int a = rest & 3;
  int kt = rest >> 2;
  if (kt >= ntiles) return;
  int k = kt * 32 + a * 8 + dp * 2;
  float x0 = (k < K) ? W[(size_t)k * HID + c] : 0.f;
  float x1 = (k + 1 < K) ? W[(size_t)(k + 1) * HID + c] : 0.f;
  unsigned short h0 = f2bf(x0), h1 = f2bf(x1);
  unsigned short l0 = f2bf(x0 - bf2f(h0)), l1 = f2bf(x1 - bf2f(h1));
  size_t o = ((size_t)(kt * 4 + a) * 256 + c) * 4 + dp;
  ph[o] = (unsigned int)h0 | ((unsigned int)h1 << 16);
  pl[o] = (unsigned int)l0 | ((unsigned int)l1 << 16);
}

// ---------- main GEMM: C[M x 256] = A[M x K] @ W, bf16x3 split via MFMA ----------
__global__ __launch_bounds__(256, 2) void gemm_kernel(
    const float* __restrict__ A, const u32x4* __restrict__ WpH, const u32x4* __restrict__ WpL,
    float* __restrict__ C, const int K, const int lda) {
  constexpr int A_PLANE = 1552;   // 96*16 + 16 pad
  constexpr int B_PLANE = 4112;   // 256*16 + 16 pad
  constexpr int AH = 0, AL = 6208, BHo = 12416, BLo = 28864;
  __shared__ __align__(16) char smem[45312];
  const int tid = threadIdx.x;
  const int l = tid & 63, w = tid >> 6;
  const int lrow = l & 15, lk = l >> 4;
  const int row0 = blockIdx.x * 96;

  f32x4 acc[6][4];
#pragma unroll
  for (int m = 0; m < 6; ++m)
#pragma unroll
    for (int n = 0; n < 4; ++n) acc[m][n] = (f32x4){0.f, 0.f, 0.f, 0.f};

  int kt = 0;
  for (int k0 = 0; k0 < K; k0 += 32, ++kt) {
    __syncthreads();
    // A staging: 96 rows x 4 chunks, reg-staged with fp32->bf16 hi/lo split
#pragma unroll
    for (int pass = 0; pass < 2; ++pass) {
      int u = tid + pass * 256;
      if (u < 384) {
        int r = u >> 2, a = u & 3;
        float xv[8];
        int kk = k0 + 8 * a;
        if (kk < K) {
          const float* ap = A + (size_t)(row0 + r) * lda + kk;
          f32x4 v0 = *(const f32x4*)ap;
          f32x4 v1 = *(const f32x4*)(ap + 4);
          xv[0] = v0[0]; xv[1] = v0[1]; xv[2] = v0[2]; xv[3] = v0[3];
          xv[4] = v1[0]; xv[5] = v1[1]; xv[6] = v1[2]; xv[7] = v1[3];
        } else {
#pragma unroll
          for (int j = 0; j < 8; ++j) xv[j] = 0.f;
        }
        unsigned int hp[4], lp[4];
        cvt8(xv, hp, lp);
        *(u32x4*)(smem + AH + a * A_PLANE + r * 16) = (u32x4){hp[0], hp[1], hp[2], hp[3]};
        *(u32x4*)(smem + AL + a * A_PLANE + r * 16) = (u32x4){lp[0], lp[1], lp[2], lp[3]};
      }
    }
    // B staging: preconverted global image -> LDS copy
    {
      const u32x4* bsrcH = WpH + (size_t)kt * 1024;
      const u32x4* bsrcL = WpL + (size_t)kt * 1024;
#pragma unroll
      for (int a = 0; a < 4; ++a) {
        u32x4 vh = bsrcH[a * 256 + tid];
        u32x4 vl = bsrcL[a * 256 + tid];
        *(u32x4*)(smem + BHo + a * B_PLANE + tid * 16) = vh;
        *(u32x4*)(smem + BLo + a * B_PLANE + tid * 16) = vl;
      }
    }
    __syncthreads();
    bf16x8 ah[6], alo[6], bh[4], blo[4];
    const char* ab = smem + lk * A_PLANE + lrow * 16;
#pragma unroll
    for (int m = 0; m < 6; ++m) {
      ah[m]  = *(const bf16x8*)(ab + AH + m * 256);
      alo[m] = *(const bf16x8*)(ab + AL + m * 256);
    }
    const char* bb = smem + lk * B_PLANE + (w * 64 + lrow) * 16;
#pragma unroll
    for (int n = 0; n < 4; ++n) {
      bh[n]  = *(const bf16x8*)(bb + BHo + n * 256);
      blo[n] = *(const bf16x8*)(bb + BLo + n * 256);
    }
#pragma unroll
    for (int m = 0; m < 6; ++m)
#pragma unroll
      for (int n = 0; n < 4; ++n) {
        acc[m][n] = __builtin_amdgcn_mfma_f32_16x16x32_bf16(ah[m], bh[n], acc[m][n], 0, 0, 0);
        acc[m][n] = __builtin_amdgcn_mfma_f32_16x16x32_bf16(ah[m], blo[n], acc[m][n], 0, 0, 0);
        acc[m][n] = __builtin_amdgcn_mfma_f32_16x16x32_bf16(alo[m], bh[n], acc[m][n], 0, 0, 0);
      }
  }
#pragma unroll
  for (int m = 0; m < 6; ++m) {
    int row = row0 + 16 * m + lk * 4;
    int col = w * 64 + lrow;
#pragma unroll
    for (int n = 0; n < 4; ++n)
#pragma unroll
      for (int i = 0; i < 4; ++i)
        C[(size_t)(row + i) * HID + col + 16 * n] = acc[m][n][i];
  }
}

// ---------- aggregation, 256 features ----------
__global__ __launch_bounds__(256) void agg256_kernel(const float* __restrict__ t, const int* __restrict__ rp,
                                                     const int* __restrict__ cs, const float* __restrict__ isq,
                                                     const float* __restrict__ idg, const float* __restrict__ bias,
                                                     float* __restrict__ out) {
  int tid = threadIdx.x;
  int q = tid & 63, nl = tid >> 6;
  int n = blockIdx.x * 4 + nl;
  int e0 = rp[n], e1 = rp[n + 1];
  const f32x4* t4 = (const f32x4*)t;
  f32x4 s = (f32x4){0.f, 0.f, 0.f, 0.f};
  for (int e = e0; e < e1; ++e) {
    int src = cs[e];
    float wv = isq[src];
    s += t4[(size_t)src * 64 + q] * wv;
  }
  f32x4 r = s * isq[n] + t4[(size_t)n * 64 + q] * idg[n] + ((const f32x4*)bias)[q];
#pragma unroll
  for (int i = 0; i < 4; ++i) r[i] = fmaxf(r[i], 0.f);
  ((f32x4*)out)[(size_t)n * 64 + q] = r;
}

// ---------- layer 5 GEMM (256 -> 16), fp32 VALU ----------
__global__ __launch_bounds__(256) void gemm16_kernel(const float* __restrict__ A, const float* __restrict__ W5,
                                                     float* __restrict__ out) {
  __shared__ float w5l[256 * 16];
  int tid = threadIdx.x;
#pragma unroll
  for (int i = 0; i < 16; ++i) { int idx = i * 256 + tid; w5l[idx] = W5[idx]; }
  __syncthreads();
  int j = tid & 15, nn = tid >> 4;
  int n = blockIdx.x * 16 + nn;
  const f32x4* A4 = (const f32x4*)(A + (size_t)n * HID);
  float acc = 0.f;
#pragma unroll 4
  for (int kq = 0; kq < 64; ++kq) {
    f32x4 a = A4[kq];
#pragma unroll
    for (int e = 0; e < 4; ++e) acc += a[e] * w5l[(kq * 4 + e) * 16 + j];
  }
  out[(size_t)n * 16 + j] = acc;
}

// ---------- aggregation, 16 features ----------
__global__ __launch_bounds__(256) void agg16_kernel(const float* __restrict__ t, const int* __restrict__ rp,
                                                    const int* __restrict__ cs, const float* __restrict__ isq,
                                                    const float* __restrict__ idg, const float* __restrict__ bias,
                                                    float* __restrict__ out) {
  int tid = threadIdx.x;
  int q = tid & 3, nl = tid >> 2;
  int n = blockIdx.x * 64 + nl;
  int e0 = rp[n], e1 = rp[n + 1];
  const f32x4* t4 = (const f32x4*)t;
  f32x4 s = (f32x4){0.f, 0.f, 0.f, 0.f};
  for (int e = e0; e < e1; ++e) {
    int src = cs[e];
    float wv = isq[src];
    s += t4[(size_t)src * 4 + q] * wv;
  }
  f32x4 r = s * isq[n] + t4[(size_t)n * 4 + q] * idg[n] + ((const f32x4*)bias)[q];
#pragma unroll
  for (int i = 0; i < 4; ++i) r[i] = fmaxf(r[i], 0.f);
  ((f32x4*)out)[(size_t)n * 4 + q] = r;
}

// ---------- LSTM input projection (both directions) ----------
__global__ __launch_bounds__(256) void xproj_kernel(const float* __restrict__ h5,
                                                    const float* __restrict__ WihF, const float* __restrict__ bihF,
                                                    const float* __restrict__ bhhF,
                                                    const float* __restrict__ WihB, const float* __restrict__ bihB,
                                                    const float* __restrict__ bhhB,
                                                    float* __restrict__ xpf, float* __restrict__ xpb) {
  __shared__ float wfl[64 * 17];
  __shared__ float wbl[64 * 17];
  __shared__ float bsF[64], bsB[64];
  int tid = threadIdx.x;
#pragma unroll
  for (int i = 0; i < 4; ++i) {
    int idx = i * 256 + tid;
    int j = idx >> 4, k = idx & 15;
    wfl[j * 17 + k] = WihF[idx];
    wbl[j * 17 + k] = WihB[idx];
  }
  if (tid < 64) { bsF[tid] = bihF[tid] + bhhF[tid]; bsB[tid] = bihB[tid] + bhhB[tid]; }
  __syncthreads();
  int j = tid & 63, nl = tid >> 6;
  int n = blockIdx.x * 4 + nl;
  const f32x4* h4 = (const f32x4*)(h5 + (size_t)n * 16);
  f32x4 sv[4];
#pragma unroll
  for (int v = 0; v < 4; ++v) sv[v] = h4[v];
  float aF = bsF[j], aB = bsB[j];
  const float* wfr = &wfl[j * 17];
  const float* wbr = &wbl[j * 17];
#pragma unroll
  for (int v = 0; v < 4; ++v)
#pragma unroll
    for (int e = 0; e < 4; ++e) {
      aF += sv[v][e] * wfr[v * 4 + e];
      aB += sv[v][e] * wbr[v * 4 + e];
    }
  xpf[(size_t)n * 64 + j] = aF;
  xpb[(size_t)n * 64 + j] = aB;
}

// ---------- bidirectional LSTM scan: 1 wave = 1 graph, both directions ----------
__global__ __launch_bounds__(64) void lstm_kernel(const float* __restrict__ xpf, const float* __restrict__ xpb,
                                                  const float* __restrict__ WhhF, const float* __restrict__ WhhB,
                                                  float* __restrict__ hn) {
  __shared__ __align__(16) float hF[16];
  __shared__ __align__(16) float hB[16];
  int b = blockIdx.x, lane = threadIdx.x;
  float wf[16], wb[16];
#pragma unroll
  for (int k = 0; k < 16; ++k) { wf[k] = WhhF[lane * 16 + k]; wb[k] = WhhB[lane * 16 + k]; }
  if (lane < 16) { hF[lane] = 0.f; hB[lane] = 0.f; }
  float cF = 0.f, cB = 0.f;
  float hFn = 0.f, hBn = 0.f;
  __syncthreads();
  const float* pf = xpf + (size_t)b * TSTEPS * 64;
  const float* pb = xpb + (size_t)b * TSTEPS * 64;
  float xf = pf[lane];
  float xb = pb[(TSTEPS - 1) * 64 + lane];
  int q = lane >> 4, kk = lane & 15;
  for (int t = 0; t < TSTEPS; ++t) {
    int tn = (t + 1 < TSTEPS) ? t + 1 : t;
    float xf_n = pf[tn * 64 + lane];
    float xb_n = pb[(TSTEPS - 1 - tn) * 64 + lane];
    float gF = xf, gB = xb;
#pragma unroll
    for (int v = 0; v < 4; ++v) {
      f32x4 hfv = ((const f32x4*)hF)[v];
      f32x4 hbv = ((const f32x4*)hB)[v];
#pragma unroll
      for (int e = 0; e < 4; ++e) {
        gF += hfv[e] * wf[v * 4 + e];
        gB += hbv[e] * wb[v * 4 + e];
      }
    }
    float aF = (q == 2) ? tanh_(gF) : sig_(gF);
    float aB = (q == 2) ? tanh_(gB) : sig_(gB);
    float iF = __shfl(aF, kk), fF = __shfl(aF, kk + 16), gFg = __shfl(aF, kk + 32), oF = __shfl(aF, kk + 48);
    float iB = __shfl(aB, kk), fB = __shfl(aB, kk + 16), gBg = __shfl(aB, kk + 32), oB = __shfl(aB, kk + 48);
    cF = fF * cF + iF * gFg;
    cB = fB * cB + iB * gBg;
    hFn = oF * tanh_(cF);
    hBn = oB * tanh_(cB);
    __syncthreads();
    if (lane < 16) { hF[kk] = hFn; hB[kk] = hBn; }
    __syncthreads();
    xf = xf_n; xb = xb_n;
  }
  if (lane < 16) {
    hn[b * 32 + kk] = hFn;
    hn[b * 32 + 16 + kk] = hBn;
  }
}

// ---------- final MLP: [64x32] -> relu(@[32x128]) -> @[128x1] ----------
__global__ __launch_bounds__(256) void mlp_kernel(const float* __restrict__ hn, const float* __restrict__ Wm1,
                                                  const float* __restrict__ bm1, const float* __restrict__ Wm2,
                                                  const float* __restrict__ bm2, float* __restrict__ out) {
  __shared__ float hnl[32 * 64];   // [k][b]
  __shared__ float w1l[32 * 128];  // [k][mm*4+mq]
  __shared__ float w2l[128], b1l[128];
  int tid = threadIdx.x;
#pragma unroll
  for (int i = 0; i < 8; ++i) { int idx = i * 256 + tid; int bb = idx >> 5, k = idx & 31; hnl[k * 64 + bb] = hn[idx]; }
#pragma unroll
  for (int i = 0; i < 16; ++i) {
    int idx = i * 256 + tid;
    int k = idx >> 7, m = idx & 127;
    w1l[k * 128 + (m & 31) * 4 + (m >> 5)] = Wm1[idx];
  }
  if (tid < 128) {
    int m = tid;
    w2l[(m & 31) * 4 + (m >> 5)] = Wm2[m];
    b1l[(m & 31) * 4 + (m >> 5)] = bm1[m];
  }
  __syncthreads();
  int b = tid >> 2, mq = tid & 3;
  float part = 0.f;
#pragma unroll 4
  for (int mm = 0; mm < 32; ++mm) {
    float a = b1l[mm * 4 + mq];
#pragma unroll
    for (int k = 0; k < 32; ++k) a += hnl[k * 64 + b] * w1l[k * 128 + mm * 4 + mq];
    part += fmaxf(a, 0.f) * w2l[mm * 4 + mq];
  }
  part += __shfl_xor(part, 1);
  part += __shfl_xor(part, 2);
  if (mq == 0) out[b] = part + bm2[0];
}

// ---------- launch ----------
extern "C" void kernel_launch(void* const* d_in, const int* in_sizes, int n_in,
                              void* d_out, int out_size, void* d_ws, size_t ws_size,
                              hipStream_t stream) {
  const float* x    = (const float*)d_in[0];
  const int*   ei   = (const int*)d_in[1];
  const float* W1   = (const float*)d_in[3];
  const float* b1   = (const float*)d_in[4];
  const float* W2   = (const float*)d_in[5];
  const float* b2   = (const float*)d_in[6];
  const float* W3   = (const float*)d_in[7];
  const float* b3   = (const float*)d_in[8];
  const float* W4   = (const float*)d_in[9];
  const float* b4   = (const float*)d_in[10];
  const float* W5   = (const float*)d_in[11];
  const float* b5   = (const float*)d_in[12];
  const float* WihF = (const float*)d_in[13];
  const float* WhhF = (const float*)d_in[14];
  const float* bihF = (const float*)d_in[15];
  const float* bhhF = (const float*)d_in[16];
  const float* WihB = (const float*)d_in[17];
  const float* WhhB = (const float*)d_in[18];
  const float* bihB = (const float*)d_in[19];
  const float* bhhB = (const float*)d_in[20];
  const float* Wm1  = (const float*)d_in[21];
  const float* bm1  = (const float*)d_in[22];
  const float* Wm2  = (const float*)d_in[23];
  const float* bm2  = (const float*)d_in[24];

  const int* esrc = ei;
  const int* edst = ei + N_EDGES;

  char* ws = (char*)d_ws;
  constexpr size_t H_A   = 0;
  constexpr size_t H_B   = 23592960;
  constexpr size_t H_T   = 47185920;
  constexpr size_t CNT   = 70778880;
  constexpr size_t CNT2  = 70871040;
  constexpr size_t RP    = 70963200;
  constexpr size_t CS    = 71055616;
  constexpr size_t ISQ   = 72530176;
  constexpr size_t IDG   = 72622336;
  constexpr size_t WP1H  = 72714496;
  constexpr size_t WP1L  = 74254592;
  constexpr size_t WP2H  = 75794688;
  constexpr size_t WP2L  = 75925760;
  constexpr size_t WP3H  = 76056832;
  constexpr size_t WP3L  = 76187904;
  constexpr size_t WP4H  = 76318976;
  constexpr size_t WP4L  = 76450048;

  float* bufA = (float*)(ws + H_A);
  float* bufB = (float*)(ws + H_B);
  float* bufT = (float*)(ws + H_T);
  int*   cnt  = (int*)(ws + CNT);
  int*   cnt2 = (int*)(ws + CNT2);
  int*   rp   = (int*)(ws + RP);
  int*   cs   = (int*)(ws + CS);
  float* isq  = (float*)(ws + ISQ);
  float* idg  = (float*)(ws + IDG);
  float* xpf  = (float*)(ws + H_B);                 // reuses bufB after layer5
  float* xpb  = (float*)(ws + H_B + 5898240);
  float* hn   = (float*)(ws + H_B + 11796480);

  hipMemsetAsync(cnt, 0, N_NODES * 4, stream);
  hipMemsetAsync(cnt2, 0, N_NODES * 4, stream);
  count_kernel<<<N_EDGES / 256, 256, 0, stream>>>(edst, cnt);
  deg_kernel<<<N_NODES / 256, 256, 0, stream>>>(cnt, isq, idg);
  scan_kernel<<<1, 1024, 0, stream>>>(cnt, rp);
  fill_kernel<<<N_EDGES / 256, 256, 0, stream>>>(esrc, edst, rp, cnt2, cs);

  prep_w_kernel<<<94 * 16, 256, 0, stream>>>(W1, 3000, 94, (unsigned int*)(ws + WP1H), (unsigned int*)(ws + WP1L));
  prep_w_kernel<<<8 * 16, 256, 0, stream>>>(W2, 256, 8, (unsigned int*)(ws + WP2H), (unsigned int*)(ws + WP2L));
  prep_w_kernel<<<8 * 16, 256, 0, stream>>>(W3, 256, 8, (unsigned int*)(ws + WP3H), (unsigned int*)(ws + WP3L));
  prep_w_kernel<<<8 * 16, 256, 0, stream>>>(W4, 256, 8, (unsigned int*)(ws + WP4H), (unsigned int*)(ws + WP4L));

  // layer 1
  gemm_kernel<<<240, 256, 0, stream>>>(x, (const u32x4*)(ws + WP1H), (const u32x4*)(ws + WP1L), bufT, 3000, 3000);
  agg256_kernel<<<N_NODES / 4, 256, 0, stream>>>(bufT, rp, cs, isq, idg, b1, bufA);
  // layer 2
  gemm_kernel<<<240, 256, 0, stream>>>(bufA, (const u32x4*)(ws + WP2H), (const u32x4*)(ws + WP2L), bufT, 256, 256);
  agg256_kernel<<<N_NODES / 4, 256, 0, stream>>>(bufT, rp, cs, isq, idg, b2, bufB);
  // layer 3
  gemm_kernel<<<240, 256, 0, stream>>>(bufB, (const u32x4*)(ws + WP3H), (const u32x4*)(ws + WP3L), bufT, 256, 256);
  agg256_kernel<<<N_NODES / 4, 256, 0, stream>>>(bufT, rp, cs, isq, idg, b3, bufA);
  // layer 4
  gemm_kernel<<<240, 256, 0, stream>>>(bufA, (const u32x4*)(ws + WP4H), (const u32x4*)(ws + WP4L), bufT, 256, 256);
  agg256_kernel<<<N_NODES / 4, 256, 0, stream>>>(bufT, rp, cs, isq, idg, b4, bufB);
  // layer 5 (256 -> 16)
  gemm16_kernel<<<N_NODES / 16, 256, 0, stream>>>(bufB, W5, bufT);
  agg16_kernel<<<N_NODES / 64, 256, 0, stream>>>(bufT, rp, cs, isq, idg, b5, bufA);

  // LSTM
  xproj_kernel<<<N_NODES / 4, 256, 0, stream>>>(bufA, WihF, bihF, bhhF, WihB, bihB, bhhB, xpf, xpb);
  lstm_kernel<<<NGRAPH, 64, 0, stream>>>(xpf, xpb, WhhF, WhhB, hn);
  mlp_kernel<<<1, 256, 0, stream>>>(hn, Wm1, bm1, Wm2, bm2, (float*)d_out);
}